// Round 8
// baseline (190.319 us; speedup 1.0000x reference)
//
#include <hip/hip_runtime.h>
#include <hip/hip_bf16.h>

typedef unsigned int u32;
typedef unsigned short u16;
typedef __attribute__((ext_vector_type(8))) short bf16x8;   // 8 bf16 in 4 VGPRs
typedef __attribute__((ext_vector_type(4))) float f32x4;

#define DI __device__ __forceinline__

DI u16 f2b(float f){
  __hip_bfloat16 b = __float2bfloat16(f);      // RNE, HW cvt
  union{__hip_bfloat16 b; u16 u;} c; c.b = b; return c.u;
}
DI float b2f(u16 u){ union{u32 i; float f;} c; c.i = ((u32)u) << 16; return c.f; }

union BU { uint4 v; bf16x8 s; };

#define HS_STRIDE 264   // bf16 elems per row (256 data + 8 pad); 528 B, 16B-aligned

// ---------------- k_pack: W3 -> MFMA B-fragment order (bf16) ----------------
// B-frag 16x16x32: lane l holds B[k=(l>>4)*8+t][n=l&15], t=0..7.
// Wp3: [nt 16][kk 8][lane 64][t 8]  <- W_in[512 + kk*32 + (l>>4)*8 + t][nt*16 + (l&15)]
__global__ __launch_bounds__(256) void k_pack(const float* __restrict__ W_in,
                                              u16* __restrict__ Wp3)
{
  int idx = blockIdx.x * 256 + threadIdx.x;    // [0, 8192)
  int l = idx & 63, g = idx >> 6;              // g = nt*8 + kk
  int nt = g >> 3, kk = g & 7;
  int lq = l >> 4, lr = l & 15;
  int n  = nt * 16 + lr;
  int k0 = 512 + kk * 32 + lq * 8;
  u16 o[8];
#pragma unroll
  for (int tt = 0; tt < 8; tt++) o[tt] = f2b(W_in[(size_t)(k0 + tt) * 256 + n]);
  *(uint4*)(Wp3 + (size_t)idx * 8) = *(uint4*)o;
}

// ---------------- k_pre: P1 = b_in + nodes@W1, P2 = nodes@W2 (bf16 MFMA) ----
// 256 blocks: rt = bid>>4 (16 row-tiles of 64), half = (bid>>3)&1, ntp = bid&7
// (2 n-tiles each). W_in read directly in B-layout (no packing dependency).
__global__ __launch_bounds__(256) void k_pre(
    const float* __restrict__ nodes, const float* __restrict__ b_in,
    const float* __restrict__ W_in, float* __restrict__ P1, float* __restrict__ P2)
{
  const int t = threadIdx.x;
  const int w = t >> 6, l = t & 63, lq = l >> 4, lr = l & 15;
  const int rt = blockIdx.x >> 4, half = (blockIdx.x >> 3) & 1, ntp = blockIdx.x & 7;

  // A-frags: nodes[row = rt*64 + 16w + lr][k = kk*32 + lq*8 + t]
  bf16x8 af[8];
  {
    const float* ap = nodes + (size_t)(rt * 64 + 16 * w + lr) * 256 + lq * 8;
#pragma unroll
    for (int kk = 0; kk < 8; kk++){
      float4 x = *(const float4*)(ap + kk * 32);
      float4 y = *(const float4*)(ap + kk * 32 + 4);
      bf16x8 a;
      a[0]=(short)f2b(x.x); a[1]=(short)f2b(x.y); a[2]=(short)f2b(x.z); a[3]=(short)f2b(x.w);
      a[4]=(short)f2b(y.x); a[5]=(short)f2b(y.y); a[6]=(short)f2b(y.z); a[7]=(short)f2b(y.w);
      af[kk] = a;
    }
  }
  float* P = half ? P2 : P1;
#pragma unroll
  for (int q = 0; q < 2; q++){
    const int nt = ntp * 2 + q;
    const int n  = nt * 16 + lr;
    f32x4 acc = {0.f, 0.f, 0.f, 0.f};
#pragma unroll
    for (int kk = 0; kk < 8; kk++){
      const int k0 = half * 256 + kk * 32 + lq * 8;
      u16 o[8];
#pragma unroll
      for (int tt = 0; tt < 8; tt++) o[tt] = f2b(W_in[(size_t)(k0 + tt) * 256 + n]);
      BU bu; bu.v = *(uint4*)o;
      acc = __builtin_amdgcn_mfma_f32_16x16x32_bf16(af[kk], bu.s, acc, 0, 0, 0);
    }
    const float bv = half ? 0.f : b_in[n];
#pragma unroll
    for (int r = 0; r < 4; r++){
      const int row = rt * 64 + 16 * w + 4 * lq + r;     // C/D: row = quad*4+reg
      P[(size_t)row * 256 + n] = acc[r] + bv;
    }
  }
}

// ---------------- k_main: one block per (b,i) ------------------------------
__global__ __launch_bounds__(256, 4) void k_main(
    const float* __restrict__ nodes, const float* __restrict__ edges,
    const u16* __restrict__ Wp3, const float* __restrict__ W_coef,
    const float* __restrict__ b_coef, const float* __restrict__ W_out,
    const float* __restrict__ b_out, const float* __restrict__ P1,
    const float* __restrict__ P2, float* __restrict__ out_nodes,
    float* __restrict__ out_h)
{
  __shared__ u16 hS[64 * HS_STRIDE];   // h (bf16), padded rows -> 33 KB
  __shared__ float coefS[64];
  __shared__ float attnS[64];
  __shared__ float resS[256];

  const int t = threadIdx.x;
  const int w = t >> 6, l = t & 63, lq = l >> 4, lr = l & 15;
  const int bi = blockIdx.x;          // b*64 + i
  const int b = bi >> 6, i = bi & 63;

  // A-frags: edge rows (j = 16w + lr), f32 -> bf16 in flight
  bf16x8 af[8];
  {
    const float* ap = edges + (size_t)bi * 16384 + (size_t)(16 * w + lr) * 256 + lq * 8;
#pragma unroll
    for (int kk = 0; kk < 8; kk++){
      float4 x = *(const float4*)(ap + kk * 32);
      float4 y = *(const float4*)(ap + kk * 32 + 4);
      bf16x8 a;
      a[0]=(short)f2b(x.x); a[1]=(short)f2b(x.y); a[2]=(short)f2b(x.z); a[3]=(short)f2b(x.w);
      a[4]=(short)f2b(y.x); a[5]=(short)f2b(y.y); a[6]=(short)f2b(y.z); a[7]=(short)f2b(y.w);
      af[kk] = a;
    }
  }

  const uint4* wp = (const uint4*)Wp3;
  float cpart[4] = {0.f, 0.f, 0.f, 0.f};
#pragma unroll
  for (int nt = 0; nt < 16; nt++){
    const int col = nt * 16 + lr;
    // issue epilogue operands early (overlap with MFMA stream)
    const float p1 = P1[(size_t)bi * 256 + col];
    const float wc = W_coef[col];
    float p2v[4];
#pragma unroll
    for (int r = 0; r < 4; r++)
      p2v[r] = P2[((size_t)b * 64 + 16 * w + 4 * lq + r) * 256 + col];

    f32x4 acc = {0.f, 0.f, 0.f, 0.f};
#pragma unroll
    for (int kk = 0; kk < 8; kk++){
      BU bu; bu.v = wp[(nt * 8 + kk) * 64 + l];
      acc = __builtin_amdgcn_mfma_f32_16x16x32_bf16(af[kk], bu.s, acc, 0, 0, 0);
    }
#pragma unroll
    for (int r = 0; r < 4; r++){
      const int row = 16 * w + 4 * lq + r;             // local j
      float h = acc[r] + p1 + p2v[r];
      h = h > 0.f ? h : 0.f;
      hS[row * HS_STRIDE + col] = f2b(h);
      cpart[r] += h * wc;
    }
  }

  // coef: reduce cpart over the 16 lanes of each quad
#pragma unroll
  for (int r = 0; r < 4; r++){
    float v = cpart[r];
    v += __shfl_xor(v, 1, 64);
    v += __shfl_xor(v, 2, 64);
    v += __shfl_xor(v, 4, 64);
    v += __shfl_xor(v, 8, 64);
    if (lr == 0) coefS[16 * w + 4 * lq + r] = v;
  }
  __syncthreads();

  // softmax over j (wave 0); b_coef shifts all coefs equally
  if (t < 64){
    int j = t;
    float val = coefS[j] + b_coef[0] - (j == i ? 1e9f : 0.f);
    float m = val;
#pragma unroll
    for (int off = 32; off >= 1; off >>= 1){ float o = __shfl_xor(m, off, 64); m = m > o ? m : o; }
    float e = __expf(val - m);
    float s = e;
#pragma unroll
    for (int off = 32; off >= 1; off >>= 1) s += __shfl_xor(s, off, 64);
    attnS[j] = e / s;
  }

  // coalesced out_h write: hS (bf16) -> out_h (f32), 8x uint4 per thread
  {
    float* op = out_h + (size_t)bi * 16384;
#pragma unroll
    for (int q = 0; q < 8; q++){
      int idx = q * 256 + t;                 // 2048 groups of 8 elems
      int row = idx >> 5, c8 = (idx & 31) * 8;
      uint4 v = *(const uint4*)(hS + row * HS_STRIDE + c8);
      const u16* e = (const u16*)&v;
      float* dp = op + row * 256 + c8;
      *(float4*)dp       = make_float4(b2f(e[0]), b2f(e[1]), b2f(e[2]), b2f(e[3]));
      *(float4*)(dp + 4) = make_float4(b2f(e[4]), b2f(e[5]), b2f(e[6]), b2f(e[7]));
    }
  }
  __syncthreads();

  // residual[d] = sum_j attn[j] * h[j][d]
  {
    const int d = t;
    float res = 0.f;
#pragma unroll 8
    for (int j = 0; j < 64; j++) res += attnS[j] * b2f(hS[j * HS_STRIDE + d]);
    resS[d] = res;
  }
  __syncthreads();

  // new_nodes = nodes + relu(res @ W_out + b_out)  (f32)
  {
    const int d = t;
    float acco = b_out[d];
    for (int k4 = 0; k4 < 64; k4++){
      float4 r4 = *(const float4*)&resS[k4 * 4];
      acco += r4.x * W_out[(size_t)(k4 * 4 + 0) * 256 + d];
      acco += r4.y * W_out[(size_t)(k4 * 4 + 1) * 256 + d];
      acco += r4.z * W_out[(size_t)(k4 * 4 + 2) * 256 + d];
      acco += r4.w * W_out[(size_t)(k4 * 4 + 3) * 256 + d];
    }
    float nv = nodes[(size_t)bi * 256 + d];
    out_nodes[(size_t)bi * 256 + d] = nv + (acco > 0.f ? acco : 0.f);
  }
}

extern "C" void kernel_launch(void* const* d_in, const int* in_sizes, int n_in,
                              void* d_out, int out_size, void* d_ws, size_t ws_size,
                              hipStream_t stream)
{
  const float* nodes  = (const float*)d_in[0];
  const float* edges  = (const float*)d_in[1];
  const float* W_in   = (const float*)d_in[2];
  const float* b_in   = (const float*)d_in[3];
  const float* W_coef = (const float*)d_in[4];
  const float* b_coef = (const float*)d_in[5];
  const float* W_out  = (const float*)d_in[6];
  const float* b_out  = (const float*)d_in[7];
  (void)in_sizes; (void)n_in; (void)out_size; (void)ws_size;

  float* P1  = (float*)d_ws;           // [1024][256] f32
  float* P2  = P1 + 262144;            // [1024][256] f32
  u16*  Wp3  = (u16*)(P2 + 262144);    // 65536 bf16 (128 KB)

  float* out_nodes = (float*)d_out;          // [1024*256] f32
  float* out_h = out_nodes + 262144;         // [65536*256] f32

  hipLaunchKernelGGL(k_pack, dim3(32),   dim3(256), 0, stream, W_in, Wp3);
  hipLaunchKernelGGL(k_pre,  dim3(256),  dim3(256), 0, stream, nodes, b_in, W_in, P1, P2);
  hipLaunchKernelGGL(k_main, dim3(1024), dim3(256), 0, stream,
                     nodes, edges, Wp3, W_coef, b_coef, W_out, b_out,
                     P1, P2, out_nodes, out_h);
}